// Round 9
// baseline (176.431 us; speedup 1.0000x reference)
//
#include <hip/hip_runtime.h>

typedef unsigned long long ull;

#define N_PTS   1000000
#define DM      128
#define DP      64
#define RNB     32
#define ENT     32
#define EFS     64
#define KOUT    10
#define NITERS  8
#define NTH     512
#define NWAVE   (NTH / 64)
#define HASHCAP 32768
#define MAXNEW  2112
#define BIGF    1e30f
#define PADKEY  0xFFFFFFFFFFFFFFFFull

__device__ __forceinline__ unsigned fkey_enc(float d) {
  unsigned b = __float_as_uint(d);
  return (b & 0x80000000u) ? ~b : (b | 0x80000000u);
}

// Principal-subspace distance. Fixed accumulation order; BIT-IDENTICAL to
// rounds 0-8 (absmax 0.0 every round). Do not perturb.
__device__ __forceinline__ float dist_p(const float* __restrict__ storage,
                                        const float* qf, float qn, int id) {
  int c = id < 0 ? 0 : (id > N_PTS - 1 ? N_PTS - 1 : id);
  const float4* row = (const float4*)(storage + (size_t)c * DM);
  float sq = 0.f, dt = 0.f;
#pragma unroll
  for (int j = 0; j < DP / 4; ++j) {
    float4 s = row[j];
    sq = fmaf(s.x, s.x, sq); sq = fmaf(s.y, s.y, sq);
    sq = fmaf(s.z, s.z, sq); sq = fmaf(s.w, s.w, sq);
    dt = fmaf(s.x, qf[4*j+0], dt); dt = fmaf(s.y, qf[4*j+1], dt);
    dt = fmaf(s.z, qf[4*j+2], dt); dt = fmaf(s.w, qf[4*j+3], dt);
  }
  float d = sq - 2.f * dt + qn;
  return (id >= N_PTS) ? BIGF : d;
}

__device__ __forceinline__ bool visit_claim(int* htab, int id) {
  unsigned h = ((unsigned)id * 2654435761u) & (HASHCAP - 1);
  while (true) {
    int cur = htab[h];
    if (cur == id) return false;
    if (cur == -1) {
      int old = atomicCAS(&htab[h], -1, id);
      if (old == -1) return true;
      if (old == id) return false;
    }
    h = (h + 1) & (HASHCAP - 1);
  }
}

__device__ __forceinline__ ull wsort64(ull key, int lane) {
#pragma unroll
  for (int k = 2; k <= 64; k <<= 1) {
#pragma unroll
    for (int j = k >> 1; j > 0; j >>= 1) {
      ull other = __shfl_xor(key, j);
      bool up = ((lane & k) == 0);
      bool lower = ((lane & j) == 0);
      ull mn = key < other ? key : other;
      ull mx = key < other ? other : key;
      key = (up == lower) ? mn : mx;
    }
  }
  return key;
}

__device__ __forceinline__ ull wbmerge64(ull key, int lane) {
#pragma unroll
  for (int j = 32; j > 0; j >>= 1) {
    ull other = __shfl_xor(key, j);
    bool lower = ((lane & j) == 0);
    ull mn = key < other ? key : other;
    ull mx = key < other ? other : key;
    key = lower ? mn : mx;
  }
  return key;
}

__device__ __forceinline__ ull wmerge(ull a, ull b, int lane) {
  ull brev = __shfl_xor(b, 63);
  ull c = a < brev ? a : brev;
  return wbmerge64(c, lane);
}

__global__ __launch_bounds__(NTH) void search_kernel(
    const float* __restrict__ query,     // B x 128
    const float* __restrict__ VT,        // 128 x 128
    const float* __restrict__ storage,   // N x 128
    const int*   __restrict__ neighbors, // N x 32
    const int*   __restrict__ entry_ids, // 32
    float* __restrict__ out)             // [B*K ids | B*K dists] as float32
{
  __shared__ int   htab[HASHCAP];          // 128 KB
  __shared__ ull   newkeys[MAXNEW];        // 16.5 KB
  __shared__ ull   wavetop[NWAVE + 4][64]; // 6 KB
  __shared__ ull   beamkey[EFS];
  __shared__ int   beam_id[EFS];
  __shared__ float qf[DM];
  __shared__ float qloc[DM];
  __shared__ float qn_s;
  __shared__ int   nc;
  __shared__ float dfull[EFS];

  const int b    = blockIdx.x;
  const int B    = gridDim.x;
  const int tid  = threadIdx.x;
  const int lane = tid & 63;
  const int wid  = tid >> 6;

  const ull FILLKEY = ((ull)fkey_enc(BIGF) << 32) | (unsigned)N_PTS;

  for (int i = tid; i < HASHCAP; i += NTH) htab[i] = -1;

  // ---- q_full = query[b] @ VT.T ----
  if (tid < DM) qloc[tid] = query[(size_t)b * DM + tid];
  __syncthreads();
  if (tid < DM) {
    const float* vrow = VT + (size_t)tid * DM;
    float acc = 0.f;
#pragma unroll 8
    for (int d = 0; d < DM; ++d) acc = fmaf(qloc[d], vrow[d], acc);
    qf[tid] = acc;
  }
  __syncthreads();
  if (tid == 0) {
    float acc = 0.f;
    for (int d = 0; d < DP; ++d) acc = fmaf(qf[d], qf[d], acc);
    qn_s = acc;
  }
  __syncthreads();
  const float qn = qn_s;

  // ---- entry stage: wave 0 ----
  if (wid == 0) {
    ull ek = PADKEY;
    if (lane < ENT) {
      int id = entry_ids[lane];
      if (visit_claim(htab, id)) {
        float d = dist_p(storage, qf, qn, id);
        ek = ((ull)fkey_enc(d) << 32) | (unsigned)id;
      }
    }
    ek = wsort64(ek, lane);
    if (ek == PADKEY) ek = FILLKEY;
    beamkey[lane] = ek;
    beam_id[lane] = (int)(ek & 0xFFFFFFFFull);
  }
  __syncthreads();

  // ---- search iterations ----
  for (int it = 0; it < NITERS; ++it) {
    ull kmax = beamkey[EFS - 1];
    if (tid == 0) nc = 0;
    __syncthreads();

    // (a) prefetch 4 neighbor ids; (b) resolve 4 claims; (c) branchless
    // straight-line evals (compiler pipelines the loads); (d) appends last.
    {
      int cids[4];
#pragma unroll
      for (int k = 0; k < 4; ++k) {
        int ci = tid + k * NTH;                 // 4*512 == EFS*RNB exactly
        int bid = beam_id[ci >> 5];
        cids[k] = (bid < N_PTS) ? neighbors[(size_t)bid * RNB + (ci & 31)]
                                : N_PTS;
      }
      bool w[4];
#pragma unroll
      for (int k = 0; k < 4; ++k)
        w[k] = (cids[k] < N_PTS) && visit_claim(htab, cids[k]);

      float dd[4];
#pragma unroll
      for (int k = 0; k < 4; ++k) {
        int ce = w[k] ? cids[k] : 0;            // dummy row 0: L1-resident
        dd[k] = dist_p(storage, qf, qn, ce);
      }
#pragma unroll
      for (int k = 0; k < 4; ++k) {
        if (w[k]) {
          ull key = ((ull)fkey_enc(dd[k]) << 32) | (unsigned)cids[k];
          if (key < kmax) { int p = atomicAdd(&nc, 1); newkeys[p] = key; }
        }
      }
    }
    __syncthreads();

    int cnt = nc;
    if (cnt == 0) break;                     // beam fixed: exact early exit

    // per-wave top-64 over candidate chunks (registers + shuffles only)
    ull tk = PADKEY;
    int nchunks = (cnt + 63) >> 6;
    for (int c = wid; c < nchunks; c += NWAVE) {
      int idx = (c << 6) + lane;
      ull v = (idx < cnt) ? newkeys[idx] : PADKEY;
      v = wsort64(v, lane);
      tk = wmerge(tk, v, lane);
    }
    wavetop[wid][lane] = tk;
    __syncthreads();

    // tree merge: 8 -> 4 (waves 0-3), then wave 0 merges 4 + beam
    if (wid < 4) {
      ull a = wavetop[2 * wid][lane];
      ull bb = wavetop[2 * wid + 1][lane];
      wavetop[NWAVE + wid][lane] = wmerge(a, bb, lane);
    }
    __syncthreads();
    if (wid == 0) {
      ull m0 = wmerge(wavetop[NWAVE + 0][lane], wavetop[NWAVE + 1][lane], lane);
      ull m1 = wmerge(wavetop[NWAVE + 2][lane], wavetop[NWAVE + 3][lane], lane);
      ull t2 = wmerge(m0, m1, lane);
      ull nb = wmerge(beamkey[lane], t2, lane);   // all keys distinct
      beamkey[lane] = nb;
      beam_id[lane] = (int)(nb & 0xFFFFFFFFull);
    }
    __syncthreads();
  }

  // ---- final: full 128-dim distances + top-k, wave 0 (order as R0-R8) ----
  if (wid == 0) {
    int id = beam_id[lane];
    int c = id < 0 ? 0 : (id > N_PTS - 1 ? N_PTS - 1 : id);
    const float4* row = (const float4*)(storage + (size_t)c * DM);
    float acc = 0.f;
#pragma unroll
    for (int j = 0; j < DM / 4; ++j) {
      float4 s = row[j];
      float dx = s.x - qf[4*j+0]; acc = fmaf(dx, dx, acc);
      dx = s.y - qf[4*j+1]; acc = fmaf(dx, dx, acc);
      dx = s.z - qf[4*j+2]; acc = fmaf(dx, dx, acc);
      dx = s.w - qf[4*j+3]; acc = fmaf(dx, dx, acc);
    }
    float dv = (id >= N_PTS) ? BIGF : acc;
    dfull[lane] = dv;
    ull fk = ((ull)fkey_enc(dv) << 32) | (unsigned)lane;
    fk = wsort64(fk, lane);
    if (lane < KOUT) {
      int pos = (int)(fk & 0xFFFFFFFFull);
      out[(size_t)b * KOUT + lane] = (float)beam_id[pos];
      out[(size_t)B * KOUT + (size_t)b * KOUT + lane] = dfull[pos];
    }
  }
}

extern "C" void kernel_launch(void* const* d_in, const int* in_sizes, int n_in,
                              void* d_out, int out_size, void* d_ws, size_t ws_size,
                              hipStream_t stream) {
  const float* query     = (const float*)d_in[0];
  const float* VT        = (const float*)d_in[1];
  const float* storage   = (const float*)d_in[2];
  const int*   neighbors = (const int*)d_in[3];
  const int*   entry_ids = (const int*)d_in[4];
  float* out = (float*)d_out;

  int B = in_sizes[0] / DM;  // 128
  search_kernel<<<B, NTH, 0, stream>>>(query, VT, storage, neighbors, entry_ids, out);
}

// Round 10
// 164.870 us; speedup vs baseline: 1.0701x; 1.0701x over previous
//
#include <hip/hip_runtime.h>

typedef unsigned long long ull;

#define N_PTS   1000000
#define DM      128
#define DP      64
#define RNB     32
#define ENT     32
#define EFS     64
#define KOUT    10
#define NITERS  8
#define NTH     512
#define NWAVE   (NTH / 64)
#define HASHCAP 32768
#define MAXNEW  2112
#define BIGF    1e30f
#define PADKEY  0xFFFFFFFFFFFFFFFFull

__device__ __forceinline__ unsigned fkey_enc(float d) {
  unsigned b = __float_as_uint(d);
  return (b & 0x80000000u) ? ~b : (b | 0x80000000u);
}

// Principal-subspace distance. Fixed accumulation order; BIT-IDENTICAL to
// rounds 0-9 (absmax 0.0 every round). Do not perturb.
__device__ __forceinline__ float dist_p(const float* __restrict__ storage,
                                        const float* qf, float qn, int id) {
  int c = id < 0 ? 0 : (id > N_PTS - 1 ? N_PTS - 1 : id);
  const float4* row = (const float4*)(storage + (size_t)c * DM);
  float sq = 0.f, dt = 0.f;
#pragma unroll
  for (int j = 0; j < DP / 4; ++j) {
    float4 s = row[j];
    sq = fmaf(s.x, s.x, sq); sq = fmaf(s.y, s.y, sq);
    sq = fmaf(s.z, s.z, sq); sq = fmaf(s.w, s.w, sq);
    dt = fmaf(s.x, qf[4*j+0], dt); dt = fmaf(s.y, qf[4*j+1], dt);
    dt = fmaf(s.z, qf[4*j+2], dt); dt = fmaf(s.w, qf[4*j+3], dt);
  }
  float d = sq - 2.f * dt + qn;
  return (id >= N_PTS) ? BIGF : d;
}

__device__ __forceinline__ bool visit_claim(int* htab, int id) {
  unsigned h = ((unsigned)id * 2654435761u) & (HASHCAP - 1);
  while (true) {
    int cur = htab[h];
    if (cur == id) return false;
    if (cur == -1) {
      int old = atomicCAS(&htab[h], -1, id);
      if (old == -1) return true;
      if (old == id) return false;
    }
    h = (h + 1) & (HASHCAP - 1);
  }
}

__device__ __forceinline__ ull wsort64(ull key, int lane) {
#pragma unroll
  for (int k = 2; k <= 64; k <<= 1) {
#pragma unroll
    for (int j = k >> 1; j > 0; j >>= 1) {
      ull other = __shfl_xor(key, j);
      bool up = ((lane & k) == 0);
      bool lower = ((lane & j) == 0);
      ull mn = key < other ? key : other;
      ull mx = key < other ? other : key;
      key = (up == lower) ? mn : mx;
    }
  }
  return key;
}

__device__ __forceinline__ ull wbmerge64(ull key, int lane) {
#pragma unroll
  for (int j = 32; j > 0; j >>= 1) {
    ull other = __shfl_xor(key, j);
    bool lower = ((lane & j) == 0);
    ull mn = key < other ? key : other;
    ull mx = key < other ? other : key;
    key = lower ? mn : mx;
  }
  return key;
}

__device__ __forceinline__ ull wmerge(ull a, ull b, int lane) {
  ull brev = __shfl_xor(b, 63);
  ull c = a < brev ? a : brev;
  return wbmerge64(c, lane);
}

__global__ __launch_bounds__(NTH) void search_kernel(
    const float* __restrict__ query,     // B x 128
    const float* __restrict__ VT,        // 128 x 128
    const float* __restrict__ storage,   // N x 128
    const int*   __restrict__ neighbors, // N x 32
    const int*   __restrict__ entry_ids, // 32
    float* __restrict__ out)             // [B*K ids | B*K dists] as float32
{
  __shared__ int   htab[HASHCAP];          // 128 KB
  __shared__ ull   newkeys[MAXNEW];        // 16.5 KB
  __shared__ ull   wavetop[NWAVE + 4][64]; // 6 KB
  __shared__ ull   beamkey[EFS];
  __shared__ int   beam_id[EFS];
  __shared__ float qf[DM];
  __shared__ float qloc[DM];
  __shared__ float qn_s;
  __shared__ int   nc;
  __shared__ float dfull[EFS];

  const int b    = blockIdx.x;
  const int B    = gridDim.x;
  const int tid  = threadIdx.x;
  const int lane = tid & 63;
  const int wid  = tid >> 6;

  const ull FILLKEY = ((ull)fkey_enc(BIGF) << 32) | (unsigned)N_PTS;

  for (int i = tid; i < HASHCAP; i += NTH) htab[i] = -1;

  // ---- q_full = query[b] @ VT.T ----
  if (tid < DM) qloc[tid] = query[(size_t)b * DM + tid];
  __syncthreads();
  if (tid < DM) {
    const float* vrow = VT + (size_t)tid * DM;
    float acc = 0.f;
#pragma unroll 8
    for (int d = 0; d < DM; ++d) acc = fmaf(qloc[d], vrow[d], acc);
    qf[tid] = acc;
  }
  __syncthreads();
  if (tid == 0) {
    float acc = 0.f;
    for (int d = 0; d < DP; ++d) acc = fmaf(qf[d], qf[d], acc);
    qn_s = acc;
  }
  __syncthreads();
  const float qn = qn_s;

  // ---- entry stage: wave 0 (claims beam members into htab) ----
  if (wid == 0) {
    ull ek = PADKEY;
    if (lane < ENT) {
      int id = entry_ids[lane];
      if (visit_claim(htab, id)) {
        float d = dist_p(storage, qf, qn, id);
        ek = ((ull)fkey_enc(d) << 32) | (unsigned)id;
      }
    }
    ek = wsort64(ek, lane);
    if (ek == PADKEY) ek = FILLKEY;
    beamkey[lane] = ek;
    beam_id[lane] = (int)(ek & 0xFFFFFFFFull);
  }
  __syncthreads();

  // ---- search iterations ----
  for (int it = 0; it < NITERS; ++it) {
    ull kmax = beamkey[EFS - 1];
    if (tid == 0) nc = 0;
    __syncthreads();

    // fused propose + eval; claim AFTER the kmax test (exact: keys are
    // fixed and kmax is non-increasing, so once-failed ids fail forever;
    // once-appended ids are in htab and blocked from re-append).
    for (int ci = tid; ci < EFS * RNB; ci += NTH) {
      int e = ci >> 5;
      int r = ci & 31;
      int bid = beam_id[e];
      if (bid >= N_PTS) continue;            // fill slot (iter 0 only)
      int cid = neighbors[(size_t)bid * RNB + r];
      float d = dist_p(storage, qf, qn, cid);
      ull key = ((ull)fkey_enc(d) << 32) | (unsigned)cid;
      if (key < kmax && visit_claim(htab, cid)) {
        int p = atomicAdd(&nc, 1);
        newkeys[p] = key;
      }
    }
    __syncthreads();

    int cnt = nc;
    if (cnt == 0) break;                     // beam fixed: exact early exit

    // per-wave top-64 over candidate chunks (registers + shuffles only)
    ull t = PADKEY;
    int nchunks = (cnt + 63) >> 6;
    for (int c = wid; c < nchunks; c += NWAVE) {
      int idx = (c << 6) + lane;
      ull v = (idx < cnt) ? newkeys[idx] : PADKEY;
      v = wsort64(v, lane);
      t = wmerge(t, v, lane);
    }
    wavetop[wid][lane] = t;
    __syncthreads();

    // tree merge: 8 -> 4 (waves 0-3), then wave 0 merges 4 + beam
    if (wid < 4) {
      ull a = wavetop[2 * wid][lane];
      ull bb = wavetop[2 * wid + 1][lane];
      wavetop[NWAVE + wid][lane] = wmerge(a, bb, lane);
    }
    __syncthreads();
    if (wid == 0) {
      ull m0 = wmerge(wavetop[NWAVE + 0][lane], wavetop[NWAVE + 1][lane], lane);
      ull m1 = wmerge(wavetop[NWAVE + 2][lane], wavetop[NWAVE + 3][lane], lane);
      ull t2 = wmerge(m0, m1, lane);
      ull nb = wmerge(beamkey[lane], t2, lane);   // all keys distinct
      beamkey[lane] = nb;
      beam_id[lane] = (int)(nb & 0xFFFFFFFFull);
    }
    __syncthreads();
  }

  // ---- final: full 128-dim distances + top-k, wave 0 (order as R0-R9) ----
  if (wid == 0) {
    int id = beam_id[lane];
    int c = id < 0 ? 0 : (id > N_PTS - 1 ? N_PTS - 1 : id);
    const float4* row = (const float4*)(storage + (size_t)c * DM);
    float acc = 0.f;
#pragma unroll
    for (int j = 0; j < DM / 4; ++j) {
      float4 s = row[j];
      float dx = s.x - qf[4*j+0]; acc = fmaf(dx, dx, acc);
      dx = s.y - qf[4*j+1]; acc = fmaf(dx, dx, acc);
      dx = s.z - qf[4*j+2]; acc = fmaf(dx, dx, acc);
      dx = s.w - qf[4*j+3]; acc = fmaf(dx, dx, acc);
    }
    float dv = (id >= N_PTS) ? BIGF : acc;
    dfull[lane] = dv;
    ull fk = ((ull)fkey_enc(dv) << 32) | (unsigned)lane;
    fk = wsort64(fk, lane);
    if (lane < KOUT) {
      int pos = (int)(fk & 0xFFFFFFFFull);
      out[(size_t)b * KOUT + lane] = (float)beam_id[pos];
      out[(size_t)B * KOUT + (size_t)b * KOUT + lane] = dfull[pos];
    }
  }
}

extern "C" void kernel_launch(void* const* d_in, const int* in_sizes, int n_in,
                              void* d_out, int out_size, void* d_ws, size_t ws_size,
                              hipStream_t stream) {
  const float* query     = (const float*)d_in[0];
  const float* VT        = (const float*)d_in[1];
  const float* storage   = (const float*)d_in[2];
  const int*   neighbors = (const int*)d_in[3];
  const int*   entry_ids = (const int*)d_in[4];
  float* out = (float*)d_out;

  int B = in_sizes[0] / DM;  // 128
  search_kernel<<<B, NTH, 0, stream>>>(query, VT, storage, neighbors, entry_ids, out);
}

// Round 11
// 113.434 us; speedup vs baseline: 1.5554x; 1.4534x over previous
//
#include <hip/hip_runtime.h>

typedef unsigned long long ull;

#define N_PTS   1000000
#define DM      128
#define DP      64
#define RNB     32
#define ENT     32
#define EFS     64
#define KOUT    10
#define N_ITERS 8
#define NTH     512
#define NWAVE   (NTH / 64)
#define HASHCAP 32768
#define MAXNEW  2112
#define BIGF    1e30f
#define PADKEY  0xFFFFFFFFFFFFFFFFull

__device__ __forceinline__ unsigned fkey_enc(float d) {
  unsigned b = __float_as_uint(d);
  return (b & 0x80000000u) ? ~b : (b | 0x80000000u);
}

// Distance in principal subspace (first 64 dims). Fixed accumulation order;
// BIT-IDENTICAL to rounds 0-10 (absmax 0.0 every round). Do not perturb.
__device__ __forceinline__ float dist_p(const float* __restrict__ storage,
                                        const float* qf, float qn, int id) {
  int c = id < 0 ? 0 : (id > N_PTS - 1 ? N_PTS - 1 : id);
  const float4* row = (const float4*)(storage + (size_t)c * DM);
  float sq = 0.f, dt = 0.f;
#pragma unroll
  for (int j = 0; j < DP / 4; ++j) {
    float4 s = row[j];
    sq = fmaf(s.x, s.x, sq); sq = fmaf(s.y, s.y, sq);
    sq = fmaf(s.z, s.z, sq); sq = fmaf(s.w, s.w, sq);
    dt = fmaf(s.x, qf[4*j+0], dt); dt = fmaf(s.y, qf[4*j+1], dt);
    dt = fmaf(s.z, qf[4*j+2], dt); dt = fmaf(s.w, qf[4*j+3], dt);
  }
  float d = sq - 2.f * dt + qn;
  return (id >= N_PTS) ? BIGF : d;
}

// Visited-set claim. true => caller evaluates (newly claimed).
// Capacity 32768 > hard insert bound (32 + 8*2048 = 16416): always terminates.
__device__ __forceinline__ bool visit_claim(int* htab, int id) {
  unsigned h = ((unsigned)id * 2654435761u) & (HASHCAP - 1);
  while (true) {
    int cur = htab[h];
    if (cur == id) return false;
    if (cur == -1) {
      int old = atomicCAS(&htab[h], -1, id);
      if (old == -1) return true;
      if (old == id) return false;
    }
    h = (h + 1) & (HASHCAP - 1);
  }
}

__device__ __forceinline__ ull wsort64(ull key, int lane) {
#pragma unroll
  for (int k = 2; k <= 64; k <<= 1) {
#pragma unroll
    for (int j = k >> 1; j > 0; j >>= 1) {
      ull other = __shfl_xor(key, j);
      bool up = ((lane & k) == 0);
      bool lower = ((lane & j) == 0);
      ull mn = key < other ? key : other;
      ull mx = key < other ? other : key;
      key = (up == lower) ? mn : mx;
    }
  }
  return key;
}

__device__ __forceinline__ ull wbmerge64(ull key, int lane) {
#pragma unroll
  for (int j = 32; j > 0; j >>= 1) {
    ull other = __shfl_xor(key, j);
    bool lower = ((lane & j) == 0);
    ull mn = key < other ? key : other;
    ull mx = key < other ? other : key;
    key = lower ? mn : mx;
  }
  return key;
}

__device__ __forceinline__ ull wmerge(ull a, ull b, int lane) {
  ull brev = __shfl_xor(b, 63);           // b reversed: descending
  ull c = a < brev ? a : brev;            // 64 smallest, bitonic
  return wbmerge64(c, lane);
}

__global__ __launch_bounds__(NTH) void search_kernel(
    const float* __restrict__ query,     // B x 128
    const float* __restrict__ VT,        // 128 x 128
    const float* __restrict__ storage,   // N x 128
    const int*   __restrict__ neighbors, // N x 32
    const int*   __restrict__ entry_ids, // 32
    float* __restrict__ out)             // [B*K ids | B*K dists] as float32
{
  __shared__ int   htab[HASHCAP];      // 128 KB
  __shared__ ull   newkeys[MAXNEW];    // 16.5 KB
  __shared__ ull   wavetop[NWAVE + 4][64]; // 6 KB
  __shared__ ull   beamkey[EFS];
  __shared__ int   beam_id[EFS];
  __shared__ float qf[DM];
  __shared__ float qloc[DM];
  __shared__ float qn_s;
  __shared__ int   nc;
  __shared__ float dfull[EFS];

  const int b    = blockIdx.x;
  const int B    = gridDim.x;
  const int tid  = threadIdx.x;
  const int lane = tid & 63;
  const int wid  = tid >> 6;

  const ull FILLKEY = ((ull)fkey_enc(BIGF) << 32) | (unsigned)N_PTS;

  // ---- init visited set ----
  for (int i = tid; i < HASHCAP; i += NTH) htab[i] = -1;

  // ---- q_full = query[b] @ VT.T ----
  if (tid < DM) qloc[tid] = query[(size_t)b * DM + tid];
  __syncthreads();
  if (tid < DM) {
    const float* vrow = VT + (size_t)tid * DM;
    float acc = 0.f;
#pragma unroll 8
    for (int d = 0; d < DM; ++d) acc = fmaf(qloc[d], vrow[d], acc);
    qf[tid] = acc;
  }
  __syncthreads();
  if (tid == 0) {
    float acc = 0.f;
    for (int d = 0; d < DP; ++d) acc = fmaf(qf[d], qf[d], acc);
    qn_s = acc;
  }
  __syncthreads();
  const float qn = qn_s;

  // ---- entry stage: wave 0 only, shuffle sort, no LDS sort ----
  if (wid == 0) {
    ull ek = PADKEY;
    if (lane < ENT) {
      int id = entry_ids[lane];
      if (visit_claim(htab, id)) {           // dedups duplicate entry ids
        float d = dist_p(storage, qf, qn, id);
        ek = ((ull)fkey_enc(d) << 32) | (unsigned)id;
      }
    }
    ek = wsort64(ek, lane);
    if (ek == PADKEY) ek = FILLKEY;
    beamkey[lane] = ek;
    beam_id[lane] = (int)(ek & 0xFFFFFFFFull);
  }
  __syncthreads();

  // ---- search iterations ----
  for (int it = 0; it < N_ITERS; ++it) {
    ull kmax = beamkey[EFS - 1];
    if (tid == 0) nc = 0;
    __syncthreads();

    // fused propose + claim + evaluate + kmax-filter
    for (int ci = tid; ci < EFS * RNB; ci += NTH) {
      int e = ci >> 5;
      int r = ci & 31;
      int bid = beam_id[e];
      if (bid >= N_PTS) continue;            // fill slot (iter 0 only)
      int cid = neighbors[(size_t)bid * RNB + r];
      if (!visit_claim(htab, cid)) continue; // exact skip: key >= kmax
      float d = dist_p(storage, qf, qn, cid);
      ull key = ((ull)fkey_enc(d) << 32) | (unsigned)cid;
      if (key < kmax) {
        int p = atomicAdd(&nc, 1);
        newkeys[p] = key;
      }
    }
    __syncthreads();

    int cnt = nc;
    if (cnt == 0) break;                     // beam fixed: exact early exit

    // per-wave top-64 over candidate chunks (registers + shuffles only)
    ull t = PADKEY;
    int nchunks = (cnt + 63) >> 6;
    for (int c = wid; c < nchunks; c += NWAVE) {
      int idx = (c << 6) + lane;
      ull v = (idx < cnt) ? newkeys[idx] : PADKEY;
      v = wsort64(v, lane);
      t = wmerge(t, v, lane);
    }
    wavetop[wid][lane] = t;
    __syncthreads();

    // tree merge: 8 -> 4 (waves 0-3), then 4 -> 1 + beam merge (wave 0)
    if (wid < 4) {
      ull a = wavetop[2 * wid][lane];
      ull bb = wavetop[2 * wid + 1][lane];
      wavetop[NWAVE + wid][lane] = wmerge(a, bb, lane);
    }
    __syncthreads();
    if (wid == 0) {
      ull m0 = wmerge(wavetop[NWAVE + 0][lane], wavetop[NWAVE + 1][lane], lane);
      ull m1 = wmerge(wavetop[NWAVE + 2][lane], wavetop[NWAVE + 3][lane], lane);
      ull t2 = wmerge(m0, m1, lane);
      ull nb = wmerge(beamkey[lane], t2, lane);   // all keys distinct
      beamkey[lane] = nb;
      beam_id[lane] = (int)(nb & 0xFFFFFFFFull);
    }
    __syncthreads();
  }

  // ---- final: full 128-dim distances + top-k, wave 0 shuffle sort ----
  if (wid == 0) {
    int id = beam_id[lane];
    int c = id < 0 ? 0 : (id > N_PTS - 1 ? N_PTS - 1 : id);
    const float4* row = (const float4*)(storage + (size_t)c * DM);
    float acc = 0.f;
#pragma unroll
    for (int j = 0; j < DM / 4; ++j) {
      float4 s = row[j];
      float dx = s.x - qf[4*j+0]; acc = fmaf(dx, dx, acc);
      dx = s.y - qf[4*j+1]; acc = fmaf(dx, dx, acc);
      dx = s.z - qf[4*j+2]; acc = fmaf(dx, dx, acc);
      dx = s.w - qf[4*j+3]; acc = fmaf(dx, dx, acc);
    }
    float dv = (id >= N_PTS) ? BIGF : acc;
    dfull[lane] = dv;
    ull fk = ((ull)fkey_enc(dv) << 32) | (unsigned)lane;  // tie-break: position
    fk = wsort64(fk, lane);
    if (lane < KOUT) {
      int pos = (int)(fk & 0xFFFFFFFFull);
      out[(size_t)b * KOUT + lane] = (float)beam_id[pos];
      out[(size_t)B * KOUT + (size_t)b * KOUT + lane] = dfull[pos];
    }
  }
}

extern "C" void kernel_launch(void* const* d_in, const int* in_sizes, int n_in,
                              void* d_out, int out_size, void* d_ws, size_t ws_size,
                              hipStream_t stream) {
  const float* query     = (const float*)d_in[0];
  const float* VT        = (const float*)d_in[1];
  const float* storage   = (const float*)d_in[2];
  const int*   neighbors = (const int*)d_in[3];
  const int*   entry_ids = (const int*)d_in[4];
  float* out = (float*)d_out;

  int B = in_sizes[0] / DM;  // 128
  search_kernel<<<B, NTH, 0, stream>>>(query, VT, storage, neighbors, entry_ids, out);
}